// Round 1
// baseline (1524.378 us; speedup 1.0000x reference)
//
#include <hip/hip_runtime.h>

typedef unsigned short u16;
typedef unsigned int u32;
typedef __attribute__((ext_vector_type(8))) short bf16x8;
typedef __attribute__((ext_vector_type(4))) float f32x4;

__device__ __forceinline__ u16 f2bf(float f) {
    u32 u = __float_as_uint(f);
    u += 0x7fffu + ((u >> 16) & 1u);
    return (u16)(u >> 16);
}

// ---------------- cast fp32 -> bf16 (vectorized x4) ----------------
__global__ __launch_bounds__(256) void cast_kernel(const float* __restrict__ src,
                                                   u16* __restrict__ dst, int n4) {
    int i = blockIdx.x * 256 + threadIdx.x;
    if (i >= n4) return;
    float4 val = ((const float4*)src)[i];
    uint2 o;
    o.x = ((u32)f2bf(val.y) << 16) | f2bf(val.x);
    o.y = ((u32)f2bf(val.w) << 16) | f2bf(val.z);
    ((uint2*)dst)[i] = o;
}

// ---------------- transpose + cast: src fp32 [1024][1024] (k,n) -> dst bf16 [1024][1024] (n,k) --------
__global__ __launch_bounds__(256) void transpose_cast(const float* __restrict__ src,
                                                      u16* __restrict__ dst) {
    __shared__ float tl[32][33];
    const int tx = threadIdx.x & 31, ty = threadIdx.x >> 5;
    const int kt = blockIdx.y * 32, nt = blockIdx.x * 32;
#pragma unroll
    for (int j = 0; j < 4; ++j)
        tl[ty + j * 8][tx] = src[(kt + ty + j * 8) * 1024 + nt + tx];
    __syncthreads();
#pragma unroll
    for (int j = 0; j < 4; ++j)
        dst[(nt + ty + j * 8) * 1024 + kt + tx] = f2bf(tl[tx][ty + j * 8]);
}

// ---------------- R_hat table: tab[h][dist] = (1+e^v)/(1+e^(v-w*dist)) / sqrt(64) --------
__global__ __launch_bounds__(256) void rtab_kernel(const float* __restrict__ wp,
                                                   const float* __restrict__ vp,
                                                   float* __restrict__ tab) {
    const int i = blockIdx.x * 256 + threadIdx.x;  // 16*2048
    const int h = i >> 11, d = i & 2047;
    const float vv = vp[h], ww = wp[h];
    tab[i] = (1.f + expf(vv)) / (1.f + expf(vv - ww * (float)d)) * 0.125f;
}

// ---------------- bf16 MFMA GEMM: C[M][N] = A[M][K] @ Bt[N][K]^T (+bias) ----------------
// A row-major lda=K, Bt row-major (transposed weights) ldb=K, C row-major ldc=N.
// 64x64 tile, BK=64, 256 threads (4 waves, each 32x32 via 2x2 of 16x16x32 MFMA).
__global__ __launch_bounds__(256) void gemm_bf16(const u16* __restrict__ A,
                                                 const u16* __restrict__ Bt,
                                                 float* __restrict__ C,
                                                 const float* __restrict__ bias,
                                                 int M, int N, int K) {
    __shared__ u16 As[64][72];
    __shared__ u16 Bs[64][72];
    const int t = threadIdx.x;
    const int lane = t & 63, wave = t >> 6;
    const int m0 = blockIdx.y * 64, n0 = blockIdx.x * 64;
    const int wm = (wave & 1) * 32, wn = (wave >> 1) * 32;
    const int fr = lane & 15, fq = lane >> 4;

    f32x4 acc00 = {0.f, 0.f, 0.f, 0.f};
    f32x4 acc01 = acc00, acc10 = acc00, acc11 = acc00;

    const int sr = t >> 2, sc = (t & 3) * 16;
    const u16* Ap = A + (size_t)(m0 + sr) * K + sc;
    const u16* Bp = Bt + (size_t)(n0 + sr) * K + sc;

    for (int k0 = 0; k0 < K; k0 += 64) {
        uint4 a0 = *(const uint4*)(Ap + k0);
        uint4 a1 = *(const uint4*)(Ap + k0 + 8);
        uint4 b0 = *(const uint4*)(Bp + k0);
        uint4 b1 = *(const uint4*)(Bp + k0 + 8);
        __syncthreads();  // protect previous iteration's LDS reads
        *(uint4*)&As[sr][sc] = a0;
        *(uint4*)&As[sr][sc + 8] = a1;
        *(uint4*)&Bs[sr][sc] = b0;
        *(uint4*)&Bs[sr][sc + 8] = b1;
        __syncthreads();
#pragma unroll
        for (int kh = 0; kh < 2; ++kh) {
            bf16x8 a_lo = *(const bf16x8*)&As[wm + fr][kh * 32 + fq * 8];
            bf16x8 a_hi = *(const bf16x8*)&As[wm + 16 + fr][kh * 32 + fq * 8];
            bf16x8 b_lo = *(const bf16x8*)&Bs[wn + fr][kh * 32 + fq * 8];
            bf16x8 b_hi = *(const bf16x8*)&Bs[wn + 16 + fr][kh * 32 + fq * 8];
            acc00 = __builtin_amdgcn_mfma_f32_16x16x32_bf16(a_lo, b_lo, acc00, 0, 0, 0);
            acc01 = __builtin_amdgcn_mfma_f32_16x16x32_bf16(a_lo, b_hi, acc01, 0, 0, 0);
            acc10 = __builtin_amdgcn_mfma_f32_16x16x32_bf16(a_hi, b_lo, acc10, 0, 0, 0);
            acc11 = __builtin_amdgcn_mfma_f32_16x16x32_bf16(a_hi, b_hi, acc11, 0, 0, 0);
        }
    }
    // epilogue: C/D layout col=lane&15, row=(lane>>4)*4+reg  [verified m89/m91]
    const int rb = m0 + wm + fq * 4;
    const int cb = n0 + wn + fr;
    f32x4 accs[2][2] = {{acc00, acc01}, {acc10, acc11}};
#pragma unroll
    for (int mi = 0; mi < 2; ++mi) {
#pragma unroll
        for (int ni = 0; ni < 2; ++ni) {
            const int col = cb + ni * 16;
            const float badd = bias ? bias[col] : 0.f;
#pragma unroll
            for (int r = 0; r < 4; ++r) {
                const int row = rb + mi * 16 + r;
                C[(size_t)row * N + col] = accs[mi][ni][r] + badd;
            }
        }
    }
}

// ---------------- flash-style causal attention with relu*R_hat gate ----------------
// qkv: fp32 [B*N][3072] rows (q|k|v, feature = h*64+d). rtab: [16][2048] (R_hat/8).
// ctxb out: bf16 [B*N][1024]. Grid: (N/64 q-tiles, B*H). 256 threads.
__global__ __launch_bounds__(256) void attn_kernel(const float* __restrict__ qkv,
                                                   const float* __restrict__ rtab,
                                                   u16* __restrict__ ctxb) {
    __shared__ u16 Qs[64][72];     // bf16 queries (keeps LDS under 64KB)
    __shared__ float Ks[64][68];
    __shared__ float Vs[64][68];
    __shared__ float Ss[64][68];
    __shared__ float alphaS[64];
    __shared__ float lS[64];

    const int t = threadIdx.x;
    const int qt = blockIdx.x, bh = blockIdx.y;
    const int b = bh >> 4, h = bh & 15;
    const int q0 = qt * 64;
    const float* rrow = rtab + (h << 11);
    const int base = b * (2048 * 3072) + (h << 6);

    // stage Q tile once (fp32 -> bf16)
    {
        const int r = t >> 2, c0 = (t & 3) * 16;
        const float* qp = qkv + base + (q0 + r) * 3072 + c0;
#pragma unroll
        for (int j = 0; j < 4; ++j) {
            float4 val = *(const float4*)(qp + j * 4);
            Qs[r][c0 + j * 4 + 0] = f2bf(val.x);
            Qs[r][c0 + j * 4 + 1] = f2bf(val.y);
            Qs[r][c0 + j * 4 + 2] = f2bf(val.z);
            Qs[r][c0 + j * 4 + 3] = f2bf(val.w);
        }
    }

    const int tq = t >> 4, tk = t & 15;
    const int qi0 = tq * 4, ki0 = tk * 4, di0 = tk * 4;
    float mreg = -1e30f, lreg = 0.f;   // live only in threads t<64 (softmax rows)
    float ctx[4][4] = {};

    for (int kt = 0; kt <= qt; ++kt) {
        const int kg0 = kt * 64;
        __syncthreads();  // protect Ks/Vs/Ss from previous iteration readers
        {   // stage K,V tiles (fp32)
            const int r = t >> 2, c0 = (t & 3) * 16;
            const float* kp = qkv + base + 1024 + (kg0 + r) * 3072 + c0;
            const float* vp = kp + 1024;
#pragma unroll
            for (int j = 0; j < 4; ++j) {
                *(float4*)&Ks[r][c0 + j * 4] = *(const float4*)(kp + j * 4);
                *(float4*)&Vs[r][c0 + j * 4] = *(const float4*)(vp + j * 4);
            }
        }
        __syncthreads();

        // scores: 4x4 register block per thread
        float s[4][4] = {};
#pragma unroll
        for (int d4 = 0; d4 < 16; ++d4) {
            float qv[4][4];
#pragma unroll
            for (int i = 0; i < 4; ++i) {
                uint2 qr = *(const uint2*)&Qs[qi0 + i][d4 * 4];
                qv[i][0] = __uint_as_float(qr.x << 16);
                qv[i][1] = __uint_as_float(qr.x & 0xffff0000u);
                qv[i][2] = __uint_as_float(qr.y << 16);
                qv[i][3] = __uint_as_float(qr.y & 0xffff0000u);
            }
#pragma unroll
            for (int j = 0; j < 4; ++j) {
                float4 kv = *(const float4*)&Ks[ki0 + j][d4 * 4];
#pragma unroll
                for (int i = 0; i < 4; ++i)
                    s[i][j] += qv[i][0] * kv.x + qv[i][1] * kv.y +
                               qv[i][2] * kv.z + qv[i][3] * kv.w;
            }
        }
        // mask + relu + R_hat gate (already /sqrt(hd)), write logits to Ss
#pragma unroll
        for (int i = 0; i < 4; ++i) {
            const int qg = q0 + qi0 + i;
            float4 o;
            float* op = (float*)&o;
#pragma unroll
            for (int j = 0; j < 4; ++j) {
                const int kg = kg0 + ki0 + j;
                float val = -1e30f;
                if (kg <= qg) val = fmaxf(s[i][j], 0.f) * rrow[qg - kg];
                op[j] = val;
            }
            *(float4*)&Ss[qi0 + i][ki0] = o;
        }
        __syncthreads();

        // online-softmax row pass (wave 0 only; thread r owns row r state)
        if (t < 64) {
            float4* srow = (float4*)&Ss[t][0];
            float mn = mreg;
#pragma unroll
            for (int c = 0; c < 16; ++c) {
                float4 val = srow[c];
                mn = fmaxf(mn, fmaxf(fmaxf(val.x, val.y), fmaxf(val.z, val.w)));
            }
            const float alpha = __expf(mreg - mn);
            float l = lreg * alpha;
#pragma unroll
            for (int c = 0; c < 16; ++c) {
                float4 val = srow[c];
                val.x = __expf(val.x - mn);
                val.y = __expf(val.y - mn);
                val.z = __expf(val.z - mn);
                val.w = __expf(val.w - mn);
                l += val.x + val.y + val.z + val.w;
                srow[c] = val;
            }
            mreg = mn;
            lreg = l;
            alphaS[t] = alpha;
        }
        __syncthreads();

        // PV accumulate: ctx = ctx*alpha + P @ V  (4 q-rows x 4 dims per thread)
#pragma unroll
        for (int i = 0; i < 4; ++i) {
            const float al = alphaS[qi0 + i];
#pragma unroll
            for (int j = 0; j < 4; ++j) ctx[i][j] *= al;
        }
#pragma unroll
        for (int k4 = 0; k4 < 16; ++k4) {
            float pvf[4][4];
#pragma unroll
            for (int i = 0; i < 4; ++i) {
                float4 p = *(const float4*)&Ss[qi0 + i][k4 * 4];
                pvf[i][0] = p.x; pvf[i][1] = p.y; pvf[i][2] = p.z; pvf[i][3] = p.w;
            }
#pragma unroll
            for (int c = 0; c < 4; ++c) {
                float4 vv = *(const float4*)&Vs[k4 * 4 + c][di0];
#pragma unroll
                for (int i = 0; i < 4; ++i) {
                    ctx[i][0] += pvf[i][c] * vv.x;
                    ctx[i][1] += pvf[i][c] * vv.y;
                    ctx[i][2] += pvf[i][c] * vv.z;
                    ctx[i][3] += pvf[i][c] * vv.w;
                }
            }
        }
    }

    if (t < 64) lS[t] = lreg;
    __syncthreads();
    // normalize + write bf16 ctx [b*N + q][h*64 + d]
#pragma unroll
    for (int i = 0; i < 4; ++i) {
        const float inv = 1.f / lS[qi0 + i];
        const int row = b * 2048 + q0 + qi0 + i;
        u16* op = ctxb + row * 1024 + (h << 6) + di0;
#pragma unroll
        for (int j = 0; j < 4; ++j) op[j] = f2bf(ctx[i][j] * inv);
    }
}

extern "C" void kernel_launch(void* const* d_in, const int* in_sizes, int n_in,
                              void* d_out, int out_size, void* d_ws, size_t ws_size,
                              hipStream_t stream) {
    const float* x  = (const float*)d_in[0];
    const float* Wq = (const float*)d_in[1];
    const float* Wk = (const float*)d_in[2];
    const float* Wv = (const float*)d_in[3];
    const float* Wo = (const float*)d_in[4];
    const float* bo = (const float*)d_in[5];
    const float* w  = (const float*)d_in[6];
    const float* v  = (const float*)d_in[7];
    float* out = (float*)d_out;

    char* w8 = (char*)d_ws;
    u16*  xb   = (u16*)(w8);                    // 8,388,608 B  : x as bf16 [4096][1024]
    u16*  Wcat = (u16*)(w8 + 8388608);          // 6,291,456 B  : (Wq|Wk|Wv)^T bf16 [3072][1024]
    u16*  Wot  = (u16*)(w8 + 14680064);         // 2,097,152 B  : Wo^T bf16 [1024][1024]
    float* qkv = (float*)(w8 + 16777216);       // 50,331,648 B : fp32 [4096][3072]
    u16*  ctxb = (u16*)(w8 + 67108864);         // 8,388,608 B  : ctx bf16 [4096][1024]
    float* rtab = (float*)(w8 + 75497472);      // 131,072 B    : R_hat/8 [16][2048]

    cast_kernel<<<4096, 256, 0, stream>>>(x, xb, 1048576);
    transpose_cast<<<dim3(32, 32), 256, 0, stream>>>(Wq, Wcat);
    transpose_cast<<<dim3(32, 32), 256, 0, stream>>>(Wk, Wcat + 1048576);
    transpose_cast<<<dim3(32, 32), 256, 0, stream>>>(Wv, Wcat + 2097152);
    transpose_cast<<<dim3(32, 32), 256, 0, stream>>>(Wo, Wot);
    rtab_kernel<<<128, 256, 0, stream>>>(w, v, rtab);

    // QKV fused projection: [4096][1024] @ [1024][3072]
    gemm_bf16<<<dim3(48, 64), 256, 0, stream>>>(xb, Wcat, qkv, nullptr, 4096, 3072, 1024);
    // attention
    attn_kernel<<<dim3(32, 32), 256, 0, stream>>>(qkv, rtab, ctxb);
    // output projection + bias: [4096][1024] @ [1024][1024]
    gemm_bf16<<<dim3(16, 64), 256, 0, stream>>>(ctxb, Wot, out, bo, 4096, 1024, 1024);
}

// Round 2
// 248.793 us; speedup vs baseline: 6.1271x; 6.1271x over previous
//
#include <hip/hip_runtime.h>

typedef unsigned short u16;
typedef unsigned int u32;
typedef __attribute__((ext_vector_type(8))) short bf16x8;
typedef __attribute__((ext_vector_type(4))) float f32x4;

__device__ __forceinline__ u16 f2bf(float f) {
    u32 u = __float_as_uint(f);
    u += 0x7fffu + ((u >> 16) & 1u);
    return (u16)(u >> 16);
}

// ---------------- cast fp32 -> bf16 (vectorized x4) ----------------
__global__ __launch_bounds__(256) void cast_kernel(const float* __restrict__ src,
                                                   u16* __restrict__ dst, int n4) {
    int i = blockIdx.x * 256 + threadIdx.x;
    if (i >= n4) return;
    float4 val = ((const float4*)src)[i];
    uint2 o;
    o.x = ((u32)f2bf(val.y) << 16) | f2bf(val.x);
    o.y = ((u32)f2bf(val.w) << 16) | f2bf(val.z);
    ((uint2*)dst)[i] = o;
}

// ---------------- transpose + cast: src fp32 [1024][1024] (k,n) -> dst bf16 [1024][1024] (n,k) --------
__global__ __launch_bounds__(256) void transpose_cast(const float* __restrict__ src,
                                                      u16* __restrict__ dst) {
    __shared__ float tl[32][33];
    const int tx = threadIdx.x & 31, ty = threadIdx.x >> 5;
    const int kt = blockIdx.y * 32, nt = blockIdx.x * 32;
#pragma unroll
    for (int j = 0; j < 4; ++j)
        tl[ty + j * 8][tx] = src[(kt + ty + j * 8) * 1024 + nt + tx];
    __syncthreads();
#pragma unroll
    for (int j = 0; j < 4; ++j)
        dst[(nt + ty + j * 8) * 1024 + kt + tx] = f2bf(tl[tx][ty + j * 8]);
}

// ---------------- R_hat table: tab[h][dist] = (1+e^v)/(1+e^(v-w*dist)) / sqrt(64) --------
__global__ __launch_bounds__(256) void rtab_kernel(const float* __restrict__ wp,
                                                   const float* __restrict__ vp,
                                                   float* __restrict__ tab) {
    const int i = blockIdx.x * 256 + threadIdx.x;  // 16*2048
    const int h = i >> 11, d = i & 2047;
    const float vv = vp[h], ww = wp[h];
    tab[i] = (1.f + expf(vv)) / (1.f + expf(vv - ww * (float)d)) * 0.125f;
}

// ---------------- bf16 MFMA GEMM: C = A[M][K] @ Bt[N][K]^T ----------------
// MODE 0: fp32 out C[row*N+col] = acc + bias[col]   (out-projection)
// MODE 1: QKV mode: col<2048 -> Cb (bf16 [4096][2048], Q|K);
//         col>=2048 -> Vtb bf16 transposed [feature=col-2048][row]  (V^T for attention)
template <int MODE>
__global__ __launch_bounds__(256) void gemm_bf16(const u16* __restrict__ A,
                                                 const u16* __restrict__ Bt,
                                                 float* __restrict__ C,
                                                 const float* __restrict__ bias,
                                                 u16* __restrict__ Cb,
                                                 u16* __restrict__ Vtb,
                                                 int M, int N, int K) {
    __shared__ u16 As[64][72];
    __shared__ u16 Bs[64][72];
    const int t = threadIdx.x;
    const int lane = t & 63, wave = t >> 6;
    const int m0 = blockIdx.y * 64, n0 = blockIdx.x * 64;
    const int wm = (wave & 1) * 32, wn = (wave >> 1) * 32;
    const int fr = lane & 15, fq = lane >> 4;

    f32x4 acc00 = {0.f, 0.f, 0.f, 0.f};
    f32x4 acc01 = acc00, acc10 = acc00, acc11 = acc00;

    const int sr = t >> 2, sc = (t & 3) * 16;
    const u16* Ap = A + (size_t)(m0 + sr) * K + sc;
    const u16* Bp = Bt + (size_t)(n0 + sr) * K + sc;

    for (int k0 = 0; k0 < K; k0 += 64) {
        uint4 a0 = *(const uint4*)(Ap + k0);
        uint4 a1 = *(const uint4*)(Ap + k0 + 8);
        uint4 b0 = *(const uint4*)(Bp + k0);
        uint4 b1 = *(const uint4*)(Bp + k0 + 8);
        __syncthreads();  // protect previous iteration's LDS reads
        *(uint4*)&As[sr][sc] = a0;
        *(uint4*)&As[sr][sc + 8] = a1;
        *(uint4*)&Bs[sr][sc] = b0;
        *(uint4*)&Bs[sr][sc + 8] = b1;
        __syncthreads();
#pragma unroll
        for (int kh = 0; kh < 2; ++kh) {
            bf16x8 a_lo = *(const bf16x8*)&As[wm + fr][kh * 32 + fq * 8];
            bf16x8 a_hi = *(const bf16x8*)&As[wm + 16 + fr][kh * 32 + fq * 8];
            bf16x8 b_lo = *(const bf16x8*)&Bs[wn + fr][kh * 32 + fq * 8];
            bf16x8 b_hi = *(const bf16x8*)&Bs[wn + 16 + fr][kh * 32 + fq * 8];
            acc00 = __builtin_amdgcn_mfma_f32_16x16x32_bf16(a_lo, b_lo, acc00, 0, 0, 0);
            acc01 = __builtin_amdgcn_mfma_f32_16x16x32_bf16(a_lo, b_hi, acc01, 0, 0, 0);
            acc10 = __builtin_amdgcn_mfma_f32_16x16x32_bf16(a_hi, b_lo, acc10, 0, 0, 0);
            acc11 = __builtin_amdgcn_mfma_f32_16x16x32_bf16(a_hi, b_hi, acc11, 0, 0, 0);
        }
    }
    // C/D layout: col=lane&15, row=(lane>>4)*4+reg  [verified m89/m91]
    const int rb = m0 + wm + fq * 4;
    const int cb = n0 + wn + fr;
    f32x4 accs[2][2] = {{acc00, acc01}, {acc10, acc11}};
#pragma unroll
    for (int mi = 0; mi < 2; ++mi) {
#pragma unroll
        for (int ni = 0; ni < 2; ++ni) {
            const int col = cb + ni * 16;
#pragma unroll
            for (int r = 0; r < 4; ++r) {
                const int row = rb + mi * 16 + r;
                if (MODE == 0) {
                    C[(size_t)row * N + col] = accs[mi][ni][r] + bias[col];
                } else {
                    if (n0 < 2048)
                        Cb[(size_t)row * 2048 + col] = f2bf(accs[mi][ni][r]);
                    else
                        Vtb[(size_t)(col - 2048) * M + row] = f2bf(accs[mi][ni][r]);
                }
            }
        }
    }
}

// ---------------- MFMA flash attention, causal, relu * R_hat gate ----------------
// qkb: bf16 [4096][2048] rows b*2048+seq, cols: Q at h*64+d, K at 1024+h*64+d
// vtb: bf16 [1024][4096]  rows h*64+d, cols b*2048+seq   (V transposed)
// rtab: fp32 [16][2048]  (R_hat / sqrt(64))
// ctxb out: bf16 [4096][1024]
// grid (16, 32): block z handles q-tiles z and 31-z (33 kt-iters each, perfect balance)
__global__ __launch_bounds__(256, 2) void attn_kernel(const u16* __restrict__ qkb,
                                                      const u16* __restrict__ vtb,
                                                      const float* __restrict__ rtab,
                                                      u16* __restrict__ ctxb) {
    __shared__ u16 Ks[64][72];       // K tile  [kseq][d]
    __shared__ u16 Vt[64][72];       // V^T tile [d][kseq]
    __shared__ u16 Ps[4][16][72];    // per-wave private P [q][kseq]
    __shared__ float rl[128];        // R_hat window for this tile-pair

    const int t = threadIdx.x;
    const int lane = t & 63, wave = t >> 6;
    const int l15 = lane & 15, quad = lane >> 4;
    const int z = blockIdx.x, bh = blockIdx.y;
    const int b = bh >> 4, h = bh & 15;
    const float* rrow = rtab + (h << 11);
    const int sr = t >> 2, sc = (t & 3) * 16;

    for (int ph = 0; ph < 2; ++ph) {
        const int qt = ph ? (31 - z) : z;
        const int q0 = qt * 64;

        // Q fragments (A operand): rows m = q0 + wave*16 + l15, k = ks*32+quad*8
        const u16* qrow = qkb + (size_t)(b * 2048 + q0 + wave * 16 + l15) * 2048 +
                          h * 64 + quad * 8;
        const bf16x8 qa0 = *(const bf16x8*)(qrow);
        const bf16x8 qa1 = *(const bf16x8*)(qrow + 32);

        f32x4 cacc[4];
#pragma unroll
        for (int i = 0; i < 4; ++i) cacc[i] = (f32x4){0.f, 0.f, 0.f, 0.f};
        float mrow[4] = {0.f, 0.f, 0.f, 0.f};   // valid: relu => scores >= 0
        float lrow[4] = {0.f, 0.f, 0.f, 0.f};
        const int lrbase = wave * 16 + quad * 4;  // local q row of acc reg r: lrbase + r

        for (int kt = 0; kt <= qt; ++kt) {
            const int kg0 = kt * 64;
            __syncthreads();  // protect Ks/Vt/rl from prior-iteration readers
            {
                const u16* kp = qkb + (size_t)(b * 2048 + kg0 + sr) * 2048 + 1024 +
                                h * 64 + sc;
                *(uint4*)&Ks[sr][sc] = *(const uint4*)kp;
                *(uint4*)&Ks[sr][sc + 8] = *(const uint4*)(kp + 8);
                const u16* vp = vtb + (size_t)(h * 64 + sr) * 4096 + b * 2048 + kg0 + sc;
                *(uint4*)&Vt[sr][sc] = *(const uint4*)vp;
                *(uint4*)&Vt[sr][sc + 8] = *(const uint4*)(vp + 8);
            }
            if (t < 128) {
                const int dist = (qt - kt) * 64 + t - 63;
                rl[t] = (dist >= 0) ? rrow[dist] : 0.f;
            }
            __syncthreads();

            // ---- S = Q @ K^T : 16q x 64k per wave, 8 MFMAs ----
            f32x4 sacc[4];
#pragma unroll
            for (int i = 0; i < 4; ++i) sacc[i] = (f32x4){0.f, 0.f, 0.f, 0.f};
#pragma unroll
            for (int ks = 0; ks < 2; ++ks) {
                const bf16x8 qa = ks ? qa1 : qa0;
#pragma unroll
                for (int nb = 0; nb < 4; ++nb) {
                    bf16x8 kb = *(const bf16x8*)&Ks[nb * 16 + l15][ks * 32 + quad * 8];
                    sacc[nb] = __builtin_amdgcn_mfma_f32_16x16x32_bf16(qa, kb, sacc[nb], 0, 0, 0);
                }
            }

            // ---- relu * gate, online softmax (rows live within one quad) ----
            float p[4][4], mx[4];
#pragma unroll
            for (int r = 0; r < 4; ++r) mx[r] = mrow[r];
#pragma unroll
            for (int nb = 0; nb < 4; ++nb) {
                const int col = nb * 16 + l15;
#pragma unroll
                for (int r = 0; r < 4; ++r) {
                    const float g = rl[lrbase + r - col + 63];  // 0 for masked (diag)
                    const float scv = fmaxf(sacc[nb][r], 0.f) * g;
                    p[nb][r] = scv;
                    mx[r] = fmaxf(mx[r], scv);
                }
            }
#pragma unroll
            for (int off = 1; off < 16; off <<= 1)
#pragma unroll
                for (int r = 0; r < 4; ++r)
                    mx[r] = fmaxf(mx[r], __shfl_xor(mx[r], off, 64));

            float alpha[4];
#pragma unroll
            for (int r = 0; r < 4; ++r) {
                alpha[r] = __expf(mrow[r] - mx[r]);
                mrow[r] = mx[r];
            }
            const bool diag = (kt == qt);
#pragma unroll
            for (int nb = 0; nb < 4; ++nb) {
                const int col = nb * 16 + l15;
#pragma unroll
                for (int r = 0; r < 4; ++r) {
                    float pv = __expf(p[nb][r] - mx[r]);
                    if (diag && (lrbase + r < col)) pv = 0.f;
                    p[nb][r] = pv;
                }
            }
            float lsum[4];
#pragma unroll
            for (int r = 0; r < 4; ++r)
                lsum[r] = (p[0][r] + p[1][r]) + (p[2][r] + p[3][r]);
#pragma unroll
            for (int off = 1; off < 16; off <<= 1)
#pragma unroll
                for (int r = 0; r < 4; ++r)
                    lsum[r] += __shfl_xor(lsum[r], off, 64);
#pragma unroll
            for (int r = 0; r < 4; ++r) lrow[r] = lrow[r] * alpha[r] + lsum[r];

            // ---- P -> wave-private LDS (C layout -> A layout round trip) ----
#pragma unroll
            for (int nb = 0; nb < 4; ++nb)
#pragma unroll
                for (int r = 0; r < 4; ++r)
                    Ps[wave][quad * 4 + r][nb * 16 + l15] = f2bf(p[nb][r]);

#pragma unroll
            for (int db = 0; db < 4; ++db)
#pragma unroll
                for (int r = 0; r < 4; ++r) cacc[db][r] *= alpha[r];

            // ---- ctx += P @ V : 8 MFMAs ----
#pragma unroll
            for (int ks = 0; ks < 2; ++ks) {
                const bf16x8 pa = *(const bf16x8*)&Ps[wave][l15][ks * 32 + quad * 8];
#pragma unroll
                for (int db = 0; db < 4; ++db) {
                    bf16x8 vb = *(const bf16x8*)&Vt[db * 16 + l15][ks * 32 + quad * 8];
                    cacc[db] = __builtin_amdgcn_mfma_f32_16x16x32_bf16(pa, vb, cacc[db], 0, 0, 0);
                }
            }
        }

        // ---- epilogue: normalize, store bf16 ctx ----
#pragma unroll
        for (int r = 0; r < 4; ++r) {
            const float inv = 1.f / lrow[r];
            const int row = b * 2048 + q0 + lrbase + r;
            u16* op = ctxb + (size_t)row * 1024 + h * 64 + l15;
#pragma unroll
            for (int db = 0; db < 4; ++db)
                op[db * 16] = f2bf(cacc[db][r] * inv);
        }
    }
}

extern "C" void kernel_launch(void* const* d_in, const int* in_sizes, int n_in,
                              void* d_out, int out_size, void* d_ws, size_t ws_size,
                              hipStream_t stream) {
    const float* x  = (const float*)d_in[0];
    const float* Wq = (const float*)d_in[1];
    const float* Wk = (const float*)d_in[2];
    const float* Wv = (const float*)d_in[3];
    const float* Wo = (const float*)d_in[4];
    const float* bo = (const float*)d_in[5];
    const float* w  = (const float*)d_in[6];
    const float* v  = (const float*)d_in[7];
    float* out = (float*)d_out;

    char* w8 = (char*)d_ws;
    u16*  xb   = (u16*)(w8);                     //  8 MB : x bf16 [4096][1024]
    u16*  Wcat = (u16*)(w8 + (8u << 20));        //  6 MB : (Wq|Wk|Wv)^T bf16 [3072][1024]
    u16*  Wot  = (u16*)(w8 + (14u << 20));       //  2 MB : Wo^T bf16 [1024][1024]
    u16*  qkb  = (u16*)(w8 + (16u << 20));       // 16 MB : Q|K bf16 [4096][2048]
    u16*  vtb  = (u16*)(w8 + (32u << 20));       //  8 MB : V^T bf16 [1024][4096]
    u16*  ctxb = (u16*)(w8 + (40u << 20));       //  8 MB : ctx bf16 [4096][1024]
    float* rtab = (float*)(w8 + (48u << 20));    // 128 KB: R_hat/8 [16][2048]

    cast_kernel<<<4096, 256, 0, stream>>>(x, xb, 1048576);
    transpose_cast<<<dim3(32, 32), 256, 0, stream>>>(Wq, Wcat);
    transpose_cast<<<dim3(32, 32), 256, 0, stream>>>(Wk, Wcat + 1048576);
    transpose_cast<<<dim3(32, 32), 256, 0, stream>>>(Wv, Wcat + 2097152);
    transpose_cast<<<dim3(32, 32), 256, 0, stream>>>(Wo, Wot);
    rtab_kernel<<<128, 256, 0, stream>>>(w, v, rtab);

    // QKV fused projection -> bf16 qkb + transposed V
    gemm_bf16<1><<<dim3(48, 64), 256, 0, stream>>>(xb, Wcat, nullptr, nullptr, qkb, vtb,
                                                   4096, 3072, 1024);
    // MFMA flash attention
    attn_kernel<<<dim3(16, 32), 256, 0, stream>>>(qkb, vtb, rtab, ctxb);
    // output projection + bias (fp32 out)
    gemm_bf16<0><<<dim3(16, 64), 256, 0, stream>>>(ctxb, Wot, out, bo, nullptr, nullptr,
                                                   4096, 1024, 1024);
}

// Round 3
// 216.501 us; speedup vs baseline: 7.0410x; 1.1492x over previous
//
#include <hip/hip_runtime.h>

typedef unsigned short u16;
typedef unsigned int u32;
typedef __attribute__((ext_vector_type(8))) short bf16x8;
typedef __attribute__((ext_vector_type(4))) float f32x4;

__device__ __forceinline__ u16 f2bf(float f) {
    u32 u = __float_as_uint(f);
    u += 0x7fffu + ((u >> 16) & 1u);
    return (u16)(u >> 16);
}

// async global->LDS DMA, 16B per lane, LDS dest = wave-uniform base + lane*16
#define GL2LDS(gp, lp)                                                                 \
    __builtin_amdgcn_global_load_lds((const __attribute__((address_space(1))) u32*)(const void*)(gp), \
                                     (__attribute__((address_space(3))) u32*)(void*)(lp), 16, 0, 0)

// ---------------- cast fp32 -> bf16 (vectorized x4) ----------------
__global__ __launch_bounds__(256) void cast_kernel(const float* __restrict__ src,
                                                   u16* __restrict__ dst, int n4) {
    int i = blockIdx.x * 256 + threadIdx.x;
    if (i >= n4) return;
    float4 val = ((const float4*)src)[i];
    uint2 o;
    o.x = ((u32)f2bf(val.y) << 16) | f2bf(val.x);
    o.y = ((u32)f2bf(val.w) << 16) | f2bf(val.z);
    ((uint2*)dst)[i] = o;
}

// ---------------- transpose+cast all 4 weight matrices in one launch ----------------
__global__ __launch_bounds__(256) void transpose4(const float* __restrict__ Wq,
                                                  const float* __restrict__ Wk,
                                                  const float* __restrict__ Wv,
                                                  const float* __restrict__ Wo,
                                                  u16* __restrict__ Wcat,
                                                  u16* __restrict__ Wot) {
    __shared__ float tl[32][33];
    const int zi = blockIdx.z;
    const float* src = (zi == 0) ? Wq : (zi == 1) ? Wk : (zi == 2) ? Wv : Wo;
    u16* dst = (zi < 3) ? (Wcat + zi * 1048576) : Wot;
    const int tx = threadIdx.x & 31, ty = threadIdx.x >> 5;
    const int kt = blockIdx.y * 32, nt = blockIdx.x * 32;
#pragma unroll
    for (int j = 0; j < 4; ++j)
        tl[ty + j * 8][tx] = src[(kt + ty + j * 8) * 1024 + nt + tx];
    __syncthreads();
#pragma unroll
    for (int j = 0; j < 4; ++j)
        dst[(nt + ty + j * 8) * 1024 + kt + tx] = f2bf(tl[tx][ty + j * 8]);
}

// ---------------- R_hat table: tab[h][dist] = (1+e^v)/(1+e^(v-w*dist)) / sqrt(64) --------
__global__ __launch_bounds__(256) void rtab_kernel(const float* __restrict__ wp,
                                                   const float* __restrict__ vp,
                                                   float* __restrict__ tab) {
    const int i = blockIdx.x * 256 + threadIdx.x;  // 16*2048
    const int h = i >> 11, d = i & 2047;
    const float vv = vp[h], ww = wp[h];
    tab[i] = (1.f + expf(vv)) / (1.f + expf(vv - ww * (float)d)) * 0.125f;
}

// ---------------- m97-style bf16 MFMA GEMM: 128x128 tile, BK=64, global_load_lds ------
// C = A[M][K] @ Bt[N][K]^T.  LDS tiles unpadded, XOR-swizzled (chunk ^= row&7).
// MODE 0: fp32 out + bias.  MODE 1: col<2048 -> Cb bf16 [M][2048]; else Vtb bf16 [col-2048][M].
template <int MODE>
__global__ __launch_bounds__(256, 3) void gemm128(const u16* __restrict__ A,
                                                  const u16* __restrict__ Bt,
                                                  float* __restrict__ C,
                                                  const float* __restrict__ bias,
                                                  u16* __restrict__ Cb,
                                                  u16* __restrict__ Vtb,
                                                  int M, int N, int K) {
    __shared__ __align__(16) u16 As[8192];  // 128 rows x 64 (swizzled 8-elem chunks)
    __shared__ __align__(16) u16 Bs[8192];
    const int t = threadIdx.x, lane = t & 63, wv = t >> 6;
    const int l15 = lane & 15, quad = lane >> 4;
    const int m0 = blockIdx.y << 7, n0 = blockIdx.x << 7;
    const int wm = (wv & 1) << 6, wn = (wv >> 1) << 6;

    f32x4 acc[4][4];
#pragma unroll
    for (int i = 0; i < 4; ++i)
#pragma unroll
        for (int j = 0; j < 4; ++j) acc[i][j] = (f32x4){0.f, 0.f, 0.f, 0.f};

    const int lrow = lane >> 3, lchunk = lane & 7;
    for (int k0 = 0; k0 < K; k0 += 64) {
#pragma unroll
        for (int c = 0; c < 4; ++c) {
            const int r0 = wv * 32 + c * 8;
            const int row = r0 + lrow;
            const int g = lchunk ^ (row & 7);
            GL2LDS(A + (size_t)(m0 + row) * K + k0 + g * 8, &As[r0 * 64]);
            GL2LDS(Bt + (size_t)(n0 + row) * K + k0 + g * 8, &Bs[r0 * 64]);
        }
        __syncthreads();  // drains global_load_lds (vmcnt) + protects prior reads
#pragma unroll
        for (int ks = 0; ks < 2; ++ks) {
            const int p = ((ks << 2) | quad) ^ (l15 & 7);
            bf16x8 af[4], bfr[4];
#pragma unroll
            for (int i = 0; i < 4; ++i) {
                af[i] = *(const bf16x8*)&As[(wm + i * 16 + l15) * 64 + p * 8];
                bfr[i] = *(const bf16x8*)&Bs[(wn + i * 16 + l15) * 64 + p * 8];
            }
#pragma unroll
            for (int mb = 0; mb < 4; ++mb)
#pragma unroll
                for (int nb = 0; nb < 4; ++nb)
                    acc[mb][nb] = __builtin_amdgcn_mfma_f32_16x16x32_bf16(af[mb], bfr[nb],
                                                                          acc[mb][nb], 0, 0, 0);
        }
        __syncthreads();  // protect LDS before next stage overwrites
    }
    // epilogue: C/D layout col=lane&15, row=(lane>>4)*4+reg
    const int rb = m0 + wm + (quad << 2);
    const int cbase = n0 + wn + l15;
#pragma unroll
    for (int mb = 0; mb < 4; ++mb)
#pragma unroll
        for (int nb = 0; nb < 4; ++nb) {
            const int col = cbase + nb * 16;
#pragma unroll
            for (int r = 0; r < 4; ++r) {
                const int row = rb + mb * 16 + r;
                if (MODE == 0) {
                    C[(size_t)row * N + col] = acc[mb][nb][r] + bias[col];
                } else {
                    if (col < 2048)
                        Cb[(size_t)row * 2048 + col] = f2bf(acc[mb][nb][r]);
                    else
                        Vtb[(size_t)(col - 2048) * 4096 + row] = f2bf(acc[mb][nb][r]);
                }
            }
        }
}

// ---------------- MFMA flash attention v2: K-split waves, fixed m=0, dbuf prefetch ----
// qkb: bf16 [4096][2048] (Q | K per row).  vtb: bf16 [1024][4096] (V^T).
// Wave w owns k-col slice w*16 (for S) and d-slice w*16 (for PV). P is block-shared.
// Softmax max fixed at 0 (scores >= 0, bounded ~10) -> no rescale; l deferred to epilogue.
__global__ __launch_bounds__(256, 2) void attn_kernel(const u16* __restrict__ qkb,
                                                      const u16* __restrict__ vtb,
                                                      const float* __restrict__ rtab,
                                                      u16* __restrict__ ctxb) {
    __shared__ __align__(16) u16 Kt[2][4096];   // [kseq][d] swizzled, 8KB x2
    __shared__ __align__(16) u16 Vt2[2][4096];  // [d][kseq] swizzled, 8KB x2
    __shared__ __align__(16) u16 Ps[64][76];    // block-shared P [q][kseq], padded
    __shared__ float rall[2048];                // R_hat/8 full row for this head
    __shared__ float lred[4][64];

    const int t = threadIdx.x, lane = t & 63, wv = t >> 6;
    const int l15 = lane & 15, quad = lane >> 4;
    const int z = blockIdx.x, bh = blockIdx.y;
    const int b = bh >> 4, h = bh & 15;

    for (int i = t; i < 2048; i += 256) rall[i] = rtab[(h << 11) + i];

    const int lrow = lane >> 3, lchunk = lane & 7;
    const int half0 = (wv & 1) * 32;

    for (int ph = 0; ph < 2; ++ph) {
        const int qt = ph ? (31 - z) : z;
        const int q0 = qt << 6;

        // Q fragments (A operand, all 64 q rows): m = mb*16+l15, k = ks*32+quad*8
        bf16x8 qa[4][2];
#pragma unroll
        for (int mb = 0; mb < 4; ++mb) {
            const u16* qrow = qkb + (size_t)(b * 2048 + q0 + mb * 16 + l15) * 2048 +
                              (h << 6) + quad * 8;
            qa[mb][0] = *(const bf16x8*)(qrow);
            qa[mb][1] = *(const bf16x8*)(qrow + 32);
        }

        f32x4 cacc[4];
#pragma unroll
        for (int i = 0; i < 4; ++i) cacc[i] = (f32x4){0.f, 0.f, 0.f, 0.f};
        float lacc[4][4] = {};

        // stage kt=0 into buffer 0
        {
            const int kg0 = 0;
#pragma unroll
            for (int c = 0; c < 4; ++c) {
                const int r0 = half0 + c * 8;
                const int row = r0 + lrow;
                const int g = lchunk ^ (row & 7);
                if (wv < 2)
                    GL2LDS(qkb + (size_t)(b * 2048 + kg0 + row) * 2048 + 1024 + (h << 6) + g * 8,
                           &Kt[0][r0 * 64]);
                else
                    GL2LDS(vtb + (size_t)((h << 6) + row) * 4096 + b * 2048 + kg0 + g * 8,
                           &Vt2[0][r0 * 64]);
            }
        }

        for (int kt = 0; kt <= qt; ++kt) {
            const int bsel = kt & 1;
            __syncthreads();  // drains staging of buf[bsel]; Ps safe to rewrite
            if (kt < qt) {    // prefetch kt+1 into other buffer
                const int kg0 = (kt + 1) << 6;
#pragma unroll
                for (int c = 0; c < 4; ++c) {
                    const int r0 = half0 + c * 8;
                    const int row = r0 + lrow;
                    const int g = lchunk ^ (row & 7);
                    if (wv < 2)
                        GL2LDS(qkb + (size_t)(b * 2048 + kg0 + row) * 2048 + 1024 + (h << 6) + g * 8,
                               &Kt[bsel ^ 1][r0 * 64]);
                    else
                        GL2LDS(vtb + (size_t)((h << 6) + row) * 4096 + b * 2048 + kg0 + g * 8,
                               &Vt2[bsel ^ 1][r0 * 64]);
                }
            }

            // ---- S = Q @ K^T : wave's 16-col slice, all 64 q rows (8 MFMA) ----
            f32x4 sacc[4];
#pragma unroll
            for (int i = 0; i < 4; ++i) sacc[i] = (f32x4){0.f, 0.f, 0.f, 0.f};
#pragma unroll
            for (int ks = 0; ks < 2; ++ks) {
                const int p = ((ks << 2) | quad) ^ (l15 & 7);
                bf16x8 kb = *(const bf16x8*)&Kt[bsel][((wv << 4) + l15) * 64 + p * 8];
#pragma unroll
                for (int mb = 0; mb < 4; ++mb)
                    sacc[mb] = __builtin_amdgcn_mfma_f32_16x16x32_bf16(qa[mb][ks], kb,
                                                                       sacc[mb], 0, 0, 0);
            }

            // ---- gate + exp (fixed m=0) + lacc + P write ----
            // row = q0+mb*16+quad*4+r (C layout), col = kt*64 + wv*16 + l15
            const int dbase = q0 - ((kt << 6) + (wv << 4) + l15);
#pragma unroll
            for (int mb = 0; mb < 4; ++mb)
#pragma unroll
                for (int r = 0; r < 4; ++r) {
                    const int dist = dbase + mb * 16 + (quad << 2) + r;
                    const int di = dist < 0 ? 0 : dist;
                    float pe = __expf(fmaxf(sacc[mb][r], 0.f) * rall[di]);
                    pe = (dist < 0) ? 0.f : pe;  // causal mask (exp would give 1)
                    lacc[mb][r] += pe;
                    Ps[mb * 16 + (quad << 2) + r][(wv << 4) + l15] = f2bf(pe);
                }
            __syncthreads();  // Ps visible to all waves

            // ---- ctx += P @ V : wave's 16-wide d-slice, all 64 q rows (8 MFMA) ----
#pragma unroll
            for (int ks = 0; ks < 2; ++ks) {
                const int p = ((ks << 2) | quad) ^ (l15 & 7);
                bf16x8 vb = *(const bf16x8*)&Vt2[bsel][((wv << 4) + l15) * 64 + p * 8];
#pragma unroll
                for (int mb = 0; mb < 4; ++mb) {
                    bf16x8 pa = *(const bf16x8*)&Ps[mb * 16 + l15][ks * 32 + quad * 8];
                    cacc[mb] = __builtin_amdgcn_mfma_f32_16x16x32_bf16(pa, vb,
                                                                       cacc[mb], 0, 0, 0);
                }
            }
        }

        // ---- epilogue: reduce l across lanes (cols) then waves; normalize; store ----
#pragma unroll
        for (int off = 1; off < 16; off <<= 1)
#pragma unroll
            for (int mb = 0; mb < 4; ++mb)
#pragma unroll
                for (int r = 0; r < 4; ++r)
                    lacc[mb][r] += __shfl_xor(lacc[mb][r], off, 16);
        if (l15 == 0) {
#pragma unroll
            for (int mb = 0; mb < 4; ++mb)
#pragma unroll
                for (int r = 0; r < 4; ++r)
                    lred[wv][mb * 16 + (quad << 2) + r] = lacc[mb][r];
        }
        __syncthreads();
#pragma unroll
        for (int mb = 0; mb < 4; ++mb)
#pragma unroll
            for (int r = 0; r < 4; ++r) {
                const int row = mb * 16 + (quad << 2) + r;
                const float lt = (lred[0][row] + lred[1][row]) + (lred[2][row] + lred[3][row]);
                const float o = cacc[mb][r] / lt;
                ctxb[(size_t)(b * 2048 + q0 + row) * 1024 + (h << 6) + (wv << 4) + l15] = f2bf(o);
            }
        if (ph == 0) __syncthreads();  // protect Kt/Vt2/Ps/lred reuse by next phase
    }
}

extern "C" void kernel_launch(void* const* d_in, const int* in_sizes, int n_in,
                              void* d_out, int out_size, void* d_ws, size_t ws_size,
                              hipStream_t stream) {
    const float* x  = (const float*)d_in[0];
    const float* Wq = (const float*)d_in[1];
    const float* Wk = (const float*)d_in[2];
    const float* Wv = (const float*)d_in[3];
    const float* Wo = (const float*)d_in[4];
    const float* bo = (const float*)d_in[5];
    const float* w  = (const float*)d_in[6];
    const float* v  = (const float*)d_in[7];
    float* out = (float*)d_out;

    char* w8 = (char*)d_ws;
    u16*  xb   = (u16*)(w8);                     //  8 MB : x bf16 [4096][1024]
    u16*  Wcat = (u16*)(w8 + (8u << 20));        //  6 MB : (Wq|Wk|Wv)^T bf16 [3072][1024]
    u16*  Wot  = (u16*)(w8 + (14u << 20));       //  2 MB : Wo^T bf16 [1024][1024]
    u16*  qkb  = (u16*)(w8 + (16u << 20));       // 16 MB : Q|K bf16 [4096][2048]
    u16*  vtb  = (u16*)(w8 + (32u << 20));       //  8 MB : V^T bf16 [1024][4096]
    u16*  ctxb = (u16*)(w8 + (40u << 20));       //  8 MB : ctx bf16 [4096][1024]
    float* rtab = (float*)(w8 + (48u << 20));    // 128 KB: R_hat/8 [16][2048]

    cast_kernel<<<4096, 256, 0, stream>>>(x, xb, 1048576);
    transpose4<<<dim3(32, 32, 4), 256, 0, stream>>>(Wq, Wk, Wv, Wo, Wcat, Wot);
    rtab_kernel<<<128, 256, 0, stream>>>(w, v, rtab);

    // QKV fused projection -> bf16 qkb + transposed V   [M=4096, N=3072, K=1024]
    gemm128<1><<<dim3(24, 32), 256, 0, stream>>>(xb, Wcat, nullptr, nullptr, qkb, vtb,
                                                 4096, 3072, 1024);
    // MFMA flash attention
    attn_kernel<<<dim3(16, 32), 256, 0, stream>>>(qkb, vtb, rtab, ctxb);
    // output projection + bias (fp32 out)   [M=4096, N=1024, K=1024]
    gemm128<0><<<dim3(8, 32), 256, 0, stream>>>(ctxb, Wot, out, bo, nullptr, nullptr,
                                                4096, 1024, 1024);
}